// Round 8
// baseline (1487.135 us; speedup 1.0000x reference)
//
#include <hip/hip_runtime.h>
#include <hip/hip_fp16.h>
#include <math.h>

// Problem constants (fixed by the reference)
constexpr int Nn  = 40000;
constexpr int Ee  = 640000;
constexpr int Fd  = 128;
constexpr int Hid = 256;
constexpr int Cc  = 20;
constexpr float GEN_EPS = 1e-7f;
constexpr float LN_EPS  = 1e-5f;
constexpr int NBK = 157;               // scatter buckets: dst>>8 (256 nodes each)

using bfrag = __attribute__((ext_vector_type(8))) short;   // 8 bf16 (4 VGPR)
using f32x4 = __attribute__((ext_vector_type(4))) float;   // 4 fp32 acc
typedef __attribute__((ext_vector_type(4))) unsigned short us4;

__device__ __forceinline__ unsigned short f2bf(float f) {
  unsigned u = __float_as_uint(f);
  u += 0x7FFF + ((u >> 16) & 1);          // RNE
  return (unsigned short)(u >> 16);
}
__device__ __forceinline__ float bf2f(unsigned short b) {
  return __uint_as_float(((unsigned)b) << 16);
}
__device__ __forceinline__ unsigned packhl(float x) {
  unsigned short hi = f2bf(x);
  unsigned short lo = f2bf(x - bf2f(hi));
  return (unsigned)hi | ((unsigned)lo << 16);
}

// ---------------- CSR build ----------------
__global__ void zero_int_k(int* __restrict__ p, int n) {
  int i = blockIdx.x * 256 + threadIdx.x;
  if (i < n) p[i] = 0;
}

// per-node counts + per-bucket counts in one pass
__global__ void count2_k(const int* __restrict__ dst, int* __restrict__ cnt,
                         int* __restrict__ bcnt) {
  int e = blockIdx.x * 256 + threadIdx.x;
  if (e < Ee) {
    int d = dst[e];
    atomicAdd(&cnt[d], 1);
    atomicAdd(&bcnt[d >> 8], 1);
  }
}

__device__ __forceinline__ int block_incl_scan256(int v) {
  int t = threadIdx.x, lane = t & 63, wid = t >> 6;
  int x = v;
  #pragma unroll
  for (int off = 1; off < 64; off <<= 1) {
    int y = __shfl_up(x, off);
    if (lane >= off) x += y;
  }
  __shared__ int wsum[4];
  if (lane == 63) wsum[wid] = x;
  __syncthreads();
  int add = 0;
  #pragma unroll
  for (int w = 0; w < 4; ++w) if (w < wid) add += wsum[w];
  return x + add;
}

__global__ __launch_bounds__(256) void blocksum_k(const int* __restrict__ cnt,
                                                  int* __restrict__ bsum, int n) {
  int i = blockIdx.x * 256 + threadIdx.x;
  int v = (i < n) ? cnt[i] : 0;
  int lane = threadIdx.x & 63, wid = threadIdx.x >> 6;
  #pragma unroll
  for (int m = 32; m >= 1; m >>= 1) v += __shfl_xor(v, m);
  __shared__ int s4[4];
  if (lane == 0) s4[wid] = v;
  __syncthreads();
  if (threadIdx.x == 0) bsum[blockIdx.x] = s4[0] + s4[1] + s4[2] + s4[3];
}

__global__ __launch_bounds__(256) void scanbsum_k(int* __restrict__ bsum, int nb) {
  int t = threadIdx.x;
  int v = (t < nb) ? bsum[t] : 0;
  int incl = block_incl_scan256(v);
  if (t < nb) bsum[t] = incl - v;   // exclusive
}

__global__ __launch_bounds__(256) void scanfinal_k(const int* __restrict__ cnt,
                                                   const int* __restrict__ bsum,
                                                   int* __restrict__ row_ptr, int n) {
  int b = blockIdx.x, t = threadIdx.x;
  int i = b * 256 + t;
  int v = (i < n) ? cnt[i] : 0;
  int incl = block_incl_scan256(v);
  if (i < n) row_ptr[i + 1] = bsum[b] + incl;
  if (b == 0 && t == 0) row_ptr[0] = 0;
}

// phase 1: scatter into compact bucket regions (good write locality)
__global__ void bscatter_k(const int* __restrict__ src, const int* __restrict__ dst,
                           const float* __restrict__ eattr,
                           const int* __restrict__ boff, int* __restrict__ bcur,
                           uint2* __restrict__ tmpse, int* __restrict__ tmpd) {
  int e = blockIdx.x * 256 + threadIdx.x;
  if (e >= Ee) return;
  int d = dst[e];
  int b = d >> 8;
  int p = boff[b] + atomicAdd(&bcur[b], 1);
  tmpse[p] = make_uint2((unsigned)src[e], __float_as_uint(eattr[e]));
  tmpd[p] = d;
}

// phase 2: per-bucket final placement; each block writes a ~33KB hot region
__global__ __launch_bounds__(256) void bfinal_k(const int* __restrict__ boff,
                                                const int* __restrict__ bcur,
                                                const uint2* __restrict__ tmpse,
                                                const int* __restrict__ tmpd,
                                                const int* __restrict__ row_ptr,
                                                int* __restrict__ cur,
                                                uint2* __restrict__ cole) {
  int b = blockIdx.x;
  int s = boff[b], n = bcur[b];
  for (int i = threadIdx.x; i < n; i += 256) {
    int d = tmpd[s + i];
    int p = row_ptr[d] + atomicAdd(&cur[d], 1);
    cole[p] = tmpse[s + i];
  }
}

// deg (incl self loop) -> dis = rsqrt(deg)
__global__ void deg_dis_k(const int* __restrict__ row_ptr, const uint2* __restrict__ cole,
                          float* __restrict__ dis) {
  int i = blockIdx.x * 256 + threadIdx.x;
  if (i >= Nn) return;
  int b = row_ptr[i], e = row_ptr[i + 1];
  float s = 1.f;                         // self-loop weight
  for (int j = b; j < e; ++j) s += __uint_as_float(cole[j].y);
  dis[i] = (s > 0.f) ? rsqrtf(s) : 0.f;
}

// ---------------- weight prep: fp32 -> MFMA-fragment-ordered bf16 hi/lo planes ----------------
__global__ void prep_w_k(const float* __restrict__ w1, const float* __restrict__ w2,
                         unsigned short* __restrict__ w1h, unsigned short* __restrict__ w1l,
                         unsigned short* __restrict__ w2h, unsigned short* __restrict__ w2l) {
  int i = blockIdx.x * 256 + threadIdx.x;
  constexpr int TOT = 3 * Fd * Hid;   // 98304
  if (i >= TOT) return;
  int j = i & 7, l = (i >> 3) & 63, tk = (i >> 9) & 63, layer = i >> 15;
  int k_lo = (l >> 4) * 4 + (j & 3) + 16 * (j >> 2);
  {
    int kc = tk >> 4, tt = tk & 15;          // w1: K=128 (kc<4), N=256 (tt<16)
    int k = kc * 32 + k_lo, c = tt * 16 + (l & 15);
    float v = w1[((size_t)layer * Fd + k) * Hid + c];
    unsigned short hi = f2bf(v);
    w1h[i] = hi; w1l[i] = f2bf(v - bf2f(hi));
  }
  {
    int kc = tk >> 3, tt = tk & 7;           // w2: K=256 (kc<8), N=128 (tt<8)
    int k = kc * 32 + k_lo, c = tt * 16 + (l & 15);
    float v = w2[((size_t)layer * Hid + k) * Fd + c];
    unsigned short hi = f2bf(v);
    w2h[i] = hi; w2l[i] = f2bf(v - bf2f(hi));
  }
}

// ---------------- fused embedding gather + layer-0 LN/ReLU ----------------
__global__ __launch_bounds__(256) void embed_ln_k(const int* __restrict__ ids,
                                                  const float* __restrict__ emb,
                                                  const float* __restrict__ g,
                                                  const float* __restrict__ b,
                                                  float* __restrict__ h,
                                                  float* __restrict__ xn,
                                                  __half* __restrict__ xnh) {
  int node = blockIdx.x * 4 + (threadIdx.x >> 6);
  int lane = threadIdx.x & 63;
  float2 v = *(const float2*)(emb + (size_t)ids[node] * Fd + lane * 2);
  *(float2*)(h + (size_t)node * Fd + lane * 2) = v;
  float s = v.x + v.y;
  #pragma unroll
  for (int m = 32; m >= 1; m >>= 1) s += __shfl_xor(s, m);
  float mu = s * (1.f / 128.f);
  float d0 = v.x - mu, d1 = v.y - mu;
  float q = d0 * d0 + d1 * d1;
  #pragma unroll
  for (int m = 32; m >= 1; m >>= 1) q += __shfl_xor(q, m);
  float rs = rsqrtf(q * (1.f / 128.f) + LN_EPS);
  float2 gg = *(const float2*)(g + lane * 2);
  float2 bb = *(const float2*)(b + lane * 2);
  float ox = fmaxf(d0 * rs * gg.x + bb.x, 0.f);
  float oy = fmaxf(d1 * rs * gg.y + bb.y, 0.f);
  *(float2*)(xn + (size_t)node * Fd + lane * 2) = make_float2(ox, oy);
  *(__half2*)(xnh + (size_t)node * Fd + lane * 2) = __floats2half2_rn(ox, oy);
}

// ---------------- GENConv aggregation: 4 nodes/wave, 8 features/lane ----------------
// 16-lane groups own one node each; 16B gathers; quarter serial depth per wave
__global__ __launch_bounds__(256) void gen_agg_k(const float* __restrict__ xn,
                                                 const __half* __restrict__ xnh,
                                                 const int* __restrict__ row_ptr,
                                                 const uint2* __restrict__ cole,
                                                 const float* __restrict__ t_ptr,
                                                 unsigned* __restrict__ h2p) {
  int wid = blockIdx.x * 4 + (threadIdx.x >> 6);
  int lane = threadIdx.x & 63;
  int sub = lane >> 4;
  int node = wid * 4 + sub;
  int f0 = (lane & 15) * 8;
  float t = t_ptr[0];
  int beg = row_ptr[node], end = row_ptr[node + 1];
  const __half* xb = xnh + f0;
  float se[8], sm[8];
  #pragma unroll
  for (int i = 0; i < 8; ++i) { se[i] = 0.f; sm[i] = 0.f; }

  for (int j = beg; j < end; j += 8) {
    int idx[8];
    #pragma unroll
    for (int k = 0; k < 8; ++k) idx[k] = (j + k < end) ? (int)cole[j + k].x : -1;
    uint4 hv[8];
    #pragma unroll
    for (int k = 0; k < 8; ++k)
      if (idx[k] >= 0) hv[k] = *(const uint4*)(xb + (size_t)idx[k] * Fd);
    #pragma unroll
    for (int k = 0; k < 8; ++k) {
      if (idx[k] >= 0) {
        const __half2* hp = (const __half2*)&hv[k];
        #pragma unroll
        for (int q = 0; q < 4; ++q) {
          float2 v = __half22float2(hp[q]);
          float m0 = v.x + GEN_EPS, m1 = v.y + GEN_EPS;
          float e0 = __expf(t * m0), e1 = __expf(t * m1);
          se[2 * q]     += e0;  se[2 * q + 1] += e1;
          sm[2 * q]      = fmaf(m0, e0, sm[2 * q]);
          sm[2 * q + 1]  = fmaf(m1, e1, sm[2 * q + 1]);
        }
      }
    }
  }

  float4 s0 = *(const float4*)(xn + (size_t)node * Fd + f0);
  float4 s1 = *(const float4*)(xn + (size_t)node * Fd + f0 + 4);
  float sf[8] = {s0.x, s0.y, s0.z, s0.w, s1.x, s1.y, s1.z, s1.w};
  unsigned o[8];
  #pragma unroll
  for (int i = 0; i < 8; ++i) o[i] = packhl(sf[i] + sm[i] / (se[i] + 1e-16f));
  *(uint4*)(h2p + (size_t)node * Fd + f0) = *(uint4*)&o[0];
  *(uint4*)(h2p + (size_t)node * Fd + f0 + 4) = *(uint4*)&o[4];
}

// ---- stage 128 K-cols of 64 rows (packed hi|lo u32) into fragment-permuted LDS ----
__device__ __forceinline__ void stage_A128(const unsigned* __restrict__ Ap,
                                           int r0, int rowStride, int kOff,
                                           unsigned short (*Ah)[136],
                                           unsigned short (*Al)[136]) {
  int t = threadIdx.x;
  int row = t >> 2;
  int base = (t & 3) * 32;
  const unsigned* sp = Ap + (size_t)(r0 + row) * rowStride + kOff + base;
  #pragma unroll
  for (int hb = 0; hb < 8; ++hb) {
    int kk0 = hb * 4;
    uint4 a = *(const uint4*)(sp + kk0);
    int d = base + 8 * ((kk0 & 15) >> 2) + 4 * (kk0 >> 4);
    us4 hi = {(unsigned short)a.x, (unsigned short)a.y,
              (unsigned short)a.z, (unsigned short)a.w};
    us4 lo = {(unsigned short)(a.x >> 16), (unsigned short)(a.y >> 16),
              (unsigned short)(a.z >> 16), (unsigned short)(a.w >> 16)};
    *(us4*)&Ah[row][d] = hi;
    *(us4*)&Al[row][d] = lo;
  }
}

// ---------------- fused MLP: gemm1 + LN + relu + gemm2 + residual + {LN/ReLU | xw} ----------------
// mode 0: H += z@W2 + b2; XN/XNh = relu(LN(H))       (layers 0,1)
// mode 2: xwdh = fp16(dis * ((H + z@W2 + b2) @ gw))  (last layer; H not stored)
__global__ __launch_bounds__(256) void mlp_k(const unsigned* __restrict__ Ap,
                                             const unsigned short* __restrict__ W1h,
                                             const unsigned short* __restrict__ W1l,
                                             const float* __restrict__ b1,
                                             const float* __restrict__ g1,
                                             const float* __restrict__ bl1,
                                             const unsigned short* __restrict__ W2h,
                                             const unsigned short* __restrict__ W2l,
                                             const float* __restrict__ b2,
                                             float* __restrict__ H,
                                             const float* __restrict__ gN,
                                             const float* __restrict__ blN,
                                             float* __restrict__ XN,
                                             __half* __restrict__ XNh,
                                             const float* __restrict__ gw,
                                             const float* __restrict__ dis,
                                             __half* __restrict__ xwdh,
                                             int mode) {
  __shared__ unsigned Zu[64][258];          // phase-2 A tile (packed hi|lo), 66KB
  __shared__ float gwS[Fd * Cc];
  unsigned short (*Ah)[136] = (unsigned short(*)[136])&Zu[0][0];
  unsigned short (*Al)[136] = (unsigned short(*)[136])((unsigned short*)&Zu[0][0] + 64 * 136);
  const int t = threadIdx.x;
  const int w = t >> 6, l = t & 63;
  const int g4 = l >> 4, cl = l & 15;
  const int r0 = blockIdx.x * 64;

  if (mode == 2) for (int i = t; i < Fd * Cc; i += 256) gwS[i] = gw[i];

  // ---- phase 1: z = relu(LN(A@W1 + b1)) ----
  stage_A128(Ap, r0, Fd, 0, Ah, Al);
  __syncthreads();
  f32x4 acc[16];
  #pragma unroll
  for (int i = 0; i < 16; ++i) acc[i] = (f32x4){0.f, 0.f, 0.f, 0.f};
  for (int kc = 0; kc < 4; ++kc) {
    bfrag ah = *(const bfrag*)&Ah[16 * w + cl][kc * 32 + g4 * 8];
    bfrag al = *(const bfrag*)&Al[16 * w + cl][kc * 32 + g4 * 8];
    const unsigned short* bh = W1h + ((size_t)(kc * 16) * 64 + l) * 8;
    const unsigned short* bl = W1l + ((size_t)(kc * 16) * 64 + l) * 8;
    #pragma unroll
    for (int tt = 0; tt < 16; ++tt) {
      bfrag vbh = *(const bfrag*)(bh + tt * 512);
      bfrag vbl = *(const bfrag*)(bl + tt * 512);
      acc[tt] = __builtin_amdgcn_mfma_f32_16x16x32_bf16(ah, vbh, acc[tt], 0, 0, 0);
      acc[tt] = __builtin_amdgcn_mfma_f32_16x16x32_bf16(ah, vbl, acc[tt], 0, 0, 0);
      acc[tt] = __builtin_amdgcn_mfma_f32_16x16x32_bf16(al, vbh, acc[tt], 0, 0, 0);
    }
  }
  __syncthreads();                          // all waves done reading A LDS

  {
    float bcol[16], gcol[16], blc[16];
    #pragma unroll
    for (int tt = 0; tt < 16; ++tt) {
      int c = 16 * tt + cl;
      bcol[tt] = b1[c]; gcol[tt] = g1[c]; blc[tt] = bl1[c];
    }
    #pragma unroll
    for (int j = 0; j < 4; ++j) {
      float x[16];
      float s = 0.f, q = 0.f;
      #pragma unroll
      for (int tt = 0; tt < 16; ++tt) {
        x[tt] = acc[tt][j] + bcol[tt];
        s += x[tt];
        q = fmaf(x[tt], x[tt], q);
      }
      #pragma unroll
      for (int m = 8; m >= 1; m >>= 1) { s += __shfl_xor(s, m); q += __shfl_xor(q, m); }
      float mu = s * (1.f / 256.f);
      float rs = rsqrtf(q * (1.f / 256.f) - mu * mu + LN_EPS);
      int rl = 16 * w + 4 * g4 + j;
      #pragma unroll
      for (int tt = 0; tt < 16; ++tt) {
        float z = fmaxf((x[tt] - mu) * rs * gcol[tt] + blc[tt], 0.f);
        Zu[rl][16 * tt + cl] = packhl(z);
      }
    }
  }
  __syncthreads();                          // z tile complete

  // ---- phase 2: out = z @ W2 ----
  f32x4 acc2[8];
  #pragma unroll
  for (int i = 0; i < 8; ++i) acc2[i] = (f32x4){0.f, 0.f, 0.f, 0.f};
  for (int kf = 0; kf < 8; ++kf) {
    uint4 p0 = *(const uint4*)&Zu[16 * w + cl][kf * 32 + 4 * g4];
    uint4 p1 = *(const uint4*)&Zu[16 * w + cl][kf * 32 + 4 * g4 + 16];
    unsigned pv[8] = {p0.x, p0.y, p0.z, p0.w, p1.x, p1.y, p1.z, p1.w};
    bfrag ah2, al2;
    #pragma unroll
    for (int i = 0; i < 8; ++i) {
      ah2[i] = (short)(pv[i] & 0xFFFF);
      al2[i] = (short)(pv[i] >> 16);
    }
    const unsigned short* bh = W2h + ((size_t)(kf * 8) * 64 + l) * 8;
    const unsigned short* bl = W2l + ((size_t)(kf * 8) * 64 + l) * 8;
    #pragma unroll
    for (int tt = 0; tt < 8; ++tt) {
      bfrag vbh = *(const bfrag*)(bh + tt * 512);
      bfrag vbl = *(const bfrag*)(bl + tt * 512);
      acc2[tt] = __builtin_amdgcn_mfma_f32_16x16x32_bf16(ah2, vbh, acc2[tt], 0, 0, 0);
      acc2[tt] = __builtin_amdgcn_mfma_f32_16x16x32_bf16(ah2, vbl, acc2[tt], 0, 0, 0);
      acc2[tt] = __builtin_amdgcn_mfma_f32_16x16x32_bf16(al2, vbh, acc2[tt], 0, 0, 0);
    }
  }

  // ---- epilogue2 ----
  float bcol[8], gcol[8], blc[8];
  #pragma unroll
  for (int tt = 0; tt < 8; ++tt) {
    int c = 16 * tt + cl;
    bcol[tt] = b2[c];
    if (mode == 0) { gcol[tt] = gN[c]; blc[tt] = blN[c]; }
  }
  #pragma unroll
  for (int j = 0; j < 4; ++j) {
    int row = r0 + 16 * w + 4 * g4 + j;
    float x[8];
    float s = 0.f, q = 0.f;
    #pragma unroll
    for (int tt = 0; tt < 8; ++tt) {
      size_t off = (size_t)row * Fd + 16 * tt + cl;
      float hv = H[off] + acc2[tt][j] + bcol[tt];
      x[tt] = hv;
      if (mode == 0) {
        H[off] = hv;
        s += hv;
        q = fmaf(hv, hv, q);
      }
    }
    if (mode == 0) {
      #pragma unroll
      for (int m = 8; m >= 1; m >>= 1) { s += __shfl_xor(s, m); q += __shfl_xor(q, m); }
      float mu = s * (1.f / 128.f);
      float rs = rsqrtf(q * (1.f / 128.f) - mu * mu + LN_EPS);
      #pragma unroll
      for (int tt = 0; tt < 8; ++tt) {
        float z = fmaxf((x[tt] - mu) * rs * gcol[tt] + blc[tt], 0.f);
        size_t off = (size_t)row * Fd + 16 * tt + cl;
        XN[off] = z;
        XNh[off] = __float2half_rn(z);
      }
    } else {
      float p[Cc];
      #pragma unroll
      for (int c = 0; c < Cc; ++c) p[c] = 0.f;
      #pragma unroll
      for (int tt = 0; tt < 8; ++tt) {
        const float* wr = &gwS[(16 * tt + cl) * Cc];
        float xv = x[tt];
        #pragma unroll
        for (int c = 0; c < Cc; ++c) p[c] = fmaf(xv, wr[c], p[c]);
      }
      #pragma unroll
      for (int m = 8; m >= 1; m >>= 1)
        #pragma unroll
        for (int c = 0; c < Cc; ++c) p[c] += __shfl_xor(p[c], m);
      float v = p[0];
      #pragma unroll
      for (int c = 1; c < Cc; ++c) if (cl == c) v = p[c];
      float v2 = p[16];
      #pragma unroll
      for (int c = 17; c < Cc; ++c) if (cl == c - 16) v2 = p[c];
      float dvr = dis[row];
      xwdh[(size_t)row * 32 + cl] = __float2half_rn(v * dvr);
      if (cl < 4) xwdh[(size_t)row * 32 + 16 + cl] = __float2half_rn(v2 * dvr);
    }
  }
}

// ---------------- GCN output ----------------
__global__ __launch_bounds__(256) void gcn_out_k(const __half* __restrict__ xwdh,
                                                 const int* __restrict__ row_ptr,
                                                 const uint2* __restrict__ cole,
                                                 const float* __restrict__ dis,
                                                 const float* __restrict__ bias,
                                                 float* __restrict__ out) {
  int node = blockIdx.x * 4 + (threadIdx.x >> 6);
  int lane = threadIdx.x & 63;
  int grp = lane / Cc, c = lane % Cc;       // grp 0..2 active, 3 = idle tail lanes
  float dv = dis[node];
  float acc = 0.f;
  int beg = row_ptr[node], end = row_ptr[node + 1];
  if (grp < 3) {
    for (int j = beg + grp; j < end; j += 3) {
      uint2 ce = cole[j];
      acc += __uint_as_float(ce.y) * __half2float(xwdh[(size_t)ce.x * 32 + c]);
    }
  }
  int l20 = lane + 20 < 64 ? lane + 20 : lane;
  int l40 = lane + 40 < 64 ? lane + 40 : lane;
  float tot = acc + __shfl(acc, l20) + __shfl(acc, l40);
  float val = 0.f;
  if (lane < Cc)
    val = dv * tot + dv * __half2float(xwdh[(size_t)node * 32 + c]) + bias[c];
  float red = (lane < Cc) ? val : -INFINITY;
  #pragma unroll
  for (int m = 32; m >= 1; m >>= 1) red = fmaxf(red, __shfl_xor(red, m));
  float ex = (lane < Cc) ? __expf(val - red) : 0.f;
  #pragma unroll
  for (int m = 32; m >= 1; m >>= 1) ex += __shfl_xor(ex, m);
  float ls = __logf(ex);
  if (lane < Cc) out[(size_t)node * Cc + c] = val - red - ls;
}

// ---------------- host ----------------
extern "C" void kernel_launch(void* const* d_in, const int* in_sizes, int n_in,
                              void* d_out, int out_size, void* d_ws, size_t ws_size,
                              hipStream_t stream) {
  const int*   x_ids = (const int*)d_in[0];
  const int*   ei    = (const int*)d_in[1];
  const int*   srcp  = ei;
  const int*   dstp  = ei + Ee;
  const float* eattr = (const float*)d_in[2];
  const float* emb   = (const float*)d_in[3];
  const float* ln_g  = (const float*)d_in[4];
  const float* ln_b  = (const float*)d_in[5];
  const float* tpar  = (const float*)d_in[6];
  const float* w1    = (const float*)d_in[7];
  const float* b1    = (const float*)d_in[8];
  const float* mg    = (const float*)d_in[9];
  const float* mb    = (const float*)d_in[10];
  const float* w2    = (const float*)d_in[11];
  const float* b2    = (const float*)d_in[12];
  const float* gw    = (const float*)d_in[13];
  const float* gb    = (const float*)d_in[14];
  float* out = (float*)d_out;

  char* ws = (char*)d_ws;
  float* h    = (float*)ws;  ws += (size_t)Nn * Fd * 4;
  float* xn   = (float*)ws;  ws += (size_t)Nn * Fd * 4;
  __half* xnh = (__half*)ws; ws += (size_t)Nn * Fd * 2;
  __half* xwdh = (__half*)ws; ws += (size_t)Nn * 32 * 2;
  float* dis  = (float*)ws;  ws += (size_t)Nn * 4;
  unsigned* h2p = (unsigned*)ws; ws += (size_t)Nn * Fd * 4;
  unsigned short* w1h = (unsigned short*)ws; ws += (size_t)3 * Fd * Hid * 2;
  unsigned short* w1l = (unsigned short*)ws; ws += (size_t)3 * Fd * Hid * 2;
  unsigned short* w2h = (unsigned short*)ws; ws += (size_t)3 * Fd * Hid * 2;
  unsigned short* w2l = (unsigned short*)ws; ws += (size_t)3 * Fd * Hid * 2;
  int* row_ptr = (int*)ws; ws += (size_t)(Nn + 16) * 4;
  int* cnt   = (int*)ws;   ws += (size_t)2 * Nn * 4;    // counts + cursors
  int* bcnt  = (int*)ws;   ws += (size_t)NBK * 4;       // bucket counts -> offsets
  int* bcur  = (int*)ws;   ws += (size_t)NBK * 4;       // bucket cursors -> sizes
  uint2* cole  = (uint2*)ws; ws += (size_t)Ee * 8;
  uint2* tmpse = (uint2*)ws; ws += (size_t)Ee * 8;
  int* tmpd  = (int*)ws;   ws += (size_t)Ee * 4;
  int* bsum  = (int*)ws;   ws += 256 * 4;
  if ((size_t)(ws - (char*)d_ws) > ws_size) return;  // workspace too small

  constexpr int NB = (Nn + 255) / 256;  // 157
  constexpr int NZ = 2 * Nn + 2 * NBK;  // cnt + cursors + bucket arrays (contiguous)

  prep_w_k<<<(3 * Fd * Hid + 255) / 256, 256, 0, stream>>>(w1, w2, w1h, w1l, w2h, w2l);

  // CSR by destination (rebuilt every call; deterministic work)
  zero_int_k<<<(NZ + 255) / 256, 256, 0, stream>>>(cnt, NZ);
  count2_k<<<2500, 256, 0, stream>>>(dstp, cnt, bcnt);
  blocksum_k<<<NB, 256, 0, stream>>>(cnt, bsum, Nn);
  scanbsum_k<<<1, 256, 0, stream>>>(bsum, NB);
  scanfinal_k<<<NB, 256, 0, stream>>>(cnt, bsum, row_ptr, Nn);
  scanbsum_k<<<1, 256, 0, stream>>>(bcnt, NBK);         // bucket offsets
  bscatter_k<<<2500, 256, 0, stream>>>(srcp, dstp, eattr, bcnt, bcur, tmpse, tmpd);
  bfinal_k<<<NBK, 256, 0, stream>>>(bcnt, bcur, tmpse, tmpd, row_ptr, cnt + Nn, cole);
  deg_dis_k<<<NB, 256, 0, stream>>>(row_ptr, cole, dis);

  embed_ln_k<<<Nn / 4, 256, 0, stream>>>(x_ids, emb, ln_g, ln_b, h, xn, xnh);

  for (int i = 0; i < 3; ++i) {
    gen_agg_k<<<Nn / 16, 256, 0, stream>>>(xn, xnh, row_ptr, cole, tpar + i, h2p);
    mlp_k<<<Nn / 64, 256, 0, stream>>>(h2p,
        w1h + (size_t)i * Fd * Hid, w1l + (size_t)i * Fd * Hid,
        b1 + i * Hid, mg + i * Hid, mb + i * Hid,
        w2h + (size_t)i * Fd * Hid, w2l + (size_t)i * Fd * Hid,
        b2 + i * Fd, h,
        ln_g + (i + 1) * Fd, ln_b + (i + 1) * Fd,
        xn, xnh, gw, dis, xwdh, (i < 2) ? 0 : 2);
  }

  gcn_out_k<<<Nn / 4, 256, 0, stream>>>(xwdh, row_ptr, cole, dis, gb, out);
}

// Round 9
// 445.544 us; speedup vs baseline: 3.3378x; 3.3378x over previous
//
#include <hip/hip_runtime.h>
#include <hip/hip_fp16.h>
#include <math.h>

// Problem constants (fixed by the reference)
constexpr int Nn  = 40000;
constexpr int Ee  = 640000;
constexpr int Fd  = 128;
constexpr int Hid = 256;
constexpr int Cc  = 20;
constexpr float GEN_EPS = 1e-7f;
constexpr float LN_EPS  = 1e-5f;

using bfrag = __attribute__((ext_vector_type(8))) short;   // 8 bf16 (4 VGPR)
using f32x4 = __attribute__((ext_vector_type(4))) float;   // 4 fp32 acc
typedef __attribute__((ext_vector_type(4))) unsigned short us4;

__device__ __forceinline__ unsigned short f2bf(float f) {
  unsigned u = __float_as_uint(f);
  u += 0x7FFF + ((u >> 16) & 1);          // RNE
  return (unsigned short)(u >> 16);
}
__device__ __forceinline__ float bf2f(unsigned short b) {
  return __uint_as_float(((unsigned)b) << 16);
}
__device__ __forceinline__ unsigned packhl(float x) {
  unsigned short hi = f2bf(x);
  unsigned short lo = f2bf(x - bf2f(hi));
  return (unsigned)hi | ((unsigned)lo << 16);
}

// ---------------- CSR build ----------------
__global__ void zero_int_k(int* __restrict__ p, int n) {
  int i = blockIdx.x * 256 + threadIdx.x;
  if (i < n) p[i] = 0;
}

__global__ void count_k(const int* __restrict__ dst, int* __restrict__ cnt) {
  int e = blockIdx.x * 256 + threadIdx.x;
  if (e < Ee) atomicAdd(&cnt[dst[e]], 1);
}

__device__ __forceinline__ int block_incl_scan256(int v) {
  int t = threadIdx.x, lane = t & 63, wid = t >> 6;
  int x = v;
  #pragma unroll
  for (int off = 1; off < 64; off <<= 1) {
    int y = __shfl_up(x, off);
    if (lane >= off) x += y;
  }
  __shared__ int wsum[4];
  if (lane == 63) wsum[wid] = x;
  __syncthreads();
  int add = 0;
  #pragma unroll
  for (int w = 0; w < 4; ++w) if (w < wid) add += wsum[w];
  return x + add;
}

__global__ __launch_bounds__(256) void blocksum_k(const int* __restrict__ cnt,
                                                  int* __restrict__ bsum, int n) {
  int i = blockIdx.x * 256 + threadIdx.x;
  int v = (i < n) ? cnt[i] : 0;
  int lane = threadIdx.x & 63, wid = threadIdx.x >> 6;
  #pragma unroll
  for (int m = 32; m >= 1; m >>= 1) v += __shfl_xor(v, m);
  __shared__ int s4[4];
  if (lane == 0) s4[wid] = v;
  __syncthreads();
  if (threadIdx.x == 0) bsum[blockIdx.x] = s4[0] + s4[1] + s4[2] + s4[3];
}

__global__ __launch_bounds__(256) void scanbsum_k(int* __restrict__ bsum, int nb) {
  int t = threadIdx.x;
  int v = (t < nb) ? bsum[t] : 0;
  int incl = block_incl_scan256(v);
  if (t < nb) bsum[t] = incl - v;   // exclusive
}

__global__ __launch_bounds__(256) void scanfinal_k(const int* __restrict__ cnt,
                                                   const int* __restrict__ bsum,
                                                   int* __restrict__ row_ptr, int n) {
  int b = blockIdx.x, t = threadIdx.x;
  int i = b * 256 + t;
  int v = (i < n) ? cnt[i] : 0;
  int incl = block_incl_scan256(v);
  if (i < n) row_ptr[i + 1] = bsum[b] + incl;
  if (b == 0 && t == 0) row_ptr[0] = 0;
}

// one 8B store per edge: {src, edge_weight}; per-node cursor atomics (low contention)
__global__ void scatter_k(const int* __restrict__ src, const int* __restrict__ dst,
                          const float* __restrict__ eattr,
                          const int* __restrict__ row_ptr, int* __restrict__ cur,
                          uint2* __restrict__ cole) {
  int e = blockIdx.x * 256 + threadIdx.x;
  if (e >= Ee) return;
  int d = dst[e];
  int p = row_ptr[d] + atomicAdd(&cur[d], 1);
  cole[p] = make_uint2((unsigned)src[e], __float_as_uint(eattr[e]));
}

// deg (incl self loop) -> dis = rsqrt(deg)
__global__ void deg_dis_k(const int* __restrict__ row_ptr, const uint2* __restrict__ cole,
                          float* __restrict__ dis) {
  int i = blockIdx.x * 256 + threadIdx.x;
  if (i >= Nn) return;
  int b = row_ptr[i], e = row_ptr[i + 1];
  float s = 1.f;                         // self-loop weight
  for (int j = b; j < e; ++j) s += __uint_as_float(cole[j].y);
  dis[i] = (s > 0.f) ? rsqrtf(s) : 0.f;
}

// ---------------- weight prep: fp32 -> MFMA-fragment-ordered bf16 hi/lo planes ----------------
__global__ void prep_w_k(const float* __restrict__ w1, const float* __restrict__ w2,
                         unsigned short* __restrict__ w1h, unsigned short* __restrict__ w1l,
                         unsigned short* __restrict__ w2h, unsigned short* __restrict__ w2l) {
  int i = blockIdx.x * 256 + threadIdx.x;
  constexpr int TOT = 3 * Fd * Hid;   // 98304
  if (i >= TOT) return;
  int j = i & 7, l = (i >> 3) & 63, tk = (i >> 9) & 63, layer = i >> 15;
  int k_lo = (l >> 4) * 4 + (j & 3) + 16 * (j >> 2);
  {
    int kc = tk >> 4, tt = tk & 15;          // w1: K=128 (kc<4), N=256 (tt<16)
    int k = kc * 32 + k_lo, c = tt * 16 + (l & 15);
    float v = w1[((size_t)layer * Fd + k) * Hid + c];
    unsigned short hi = f2bf(v);
    w1h[i] = hi; w1l[i] = f2bf(v - bf2f(hi));
  }
  {
    int kc = tk >> 3, tt = tk & 7;           // w2: K=256 (kc<8), N=128 (tt<8)
    int k = kc * 32 + k_lo, c = tt * 16 + (l & 15);
    float v = w2[((size_t)layer * Hid + k) * Fd + c];
    unsigned short hi = f2bf(v);
    w2h[i] = hi; w2l[i] = f2bf(v - bf2f(hi));
  }
}

// ---------------- fused embedding gather + layer-0 LN/ReLU ----------------
__global__ __launch_bounds__(256) void embed_ln_k(const int* __restrict__ ids,
                                                  const float* __restrict__ emb,
                                                  const float* __restrict__ g,
                                                  const float* __restrict__ b,
                                                  float* __restrict__ h,
                                                  float* __restrict__ xn,
                                                  __half* __restrict__ xnh) {
  int node = blockIdx.x * 4 + (threadIdx.x >> 6);
  int lane = threadIdx.x & 63;
  float2 v = *(const float2*)(emb + (size_t)ids[node] * Fd + lane * 2);
  *(float2*)(h + (size_t)node * Fd + lane * 2) = v;
  float s = v.x + v.y;
  #pragma unroll
  for (int m = 32; m >= 1; m >>= 1) s += __shfl_xor(s, m);
  float mu = s * (1.f / 128.f);
  float d0 = v.x - mu, d1 = v.y - mu;
  float q = d0 * d0 + d1 * d1;
  #pragma unroll
  for (int m = 32; m >= 1; m >>= 1) q += __shfl_xor(q, m);
  float rs = rsqrtf(q * (1.f / 128.f) + LN_EPS);
  float2 gg = *(const float2*)(g + lane * 2);
  float2 bb = *(const float2*)(b + lane * 2);
  float ox = fmaxf(d0 * rs * gg.x + bb.x, 0.f);
  float oy = fmaxf(d1 * rs * gg.y + bb.y, 0.f);
  *(float2*)(xn + (size_t)node * Fd + lane * 2) = make_float2(ox, oy);
  *(__half2*)(xnh + (size_t)node * Fd + lane * 2) = __floats2half2_rn(ox, oy);
}

// ---------------- GENConv aggregation: 4 nodes/wave, 8 features/lane ----------------
__global__ __launch_bounds__(256) void gen_agg_k(const float* __restrict__ xn,
                                                 const __half* __restrict__ xnh,
                                                 const int* __restrict__ row_ptr,
                                                 const uint2* __restrict__ cole,
                                                 const float* __restrict__ t_ptr,
                                                 unsigned* __restrict__ h2p) {
  int wid = blockIdx.x * 4 + (threadIdx.x >> 6);
  int lane = threadIdx.x & 63;
  int sub = lane >> 4;
  int node = wid * 4 + sub;
  int f0 = (lane & 15) * 8;
  float t = t_ptr[0];
  int beg = row_ptr[node], end = row_ptr[node + 1];
  const __half* xb = xnh + f0;
  float se[8], sm[8];
  #pragma unroll
  for (int i = 0; i < 8; ++i) { se[i] = 0.f; sm[i] = 0.f; }

  for (int j = beg; j < end; j += 8) {
    int idx[8];
    #pragma unroll
    for (int k = 0; k < 8; ++k) idx[k] = (j + k < end) ? (int)cole[j + k].x : -1;
    uint4 hv[8];
    #pragma unroll
    for (int k = 0; k < 8; ++k)
      if (idx[k] >= 0) hv[k] = *(const uint4*)(xb + (size_t)idx[k] * Fd);
    #pragma unroll
    for (int k = 0; k < 8; ++k) {
      if (idx[k] >= 0) {
        const __half2* hp = (const __half2*)&hv[k];
        #pragma unroll
        for (int q = 0; q < 4; ++q) {
          float2 v = __half22float2(hp[q]);
          float m0 = v.x + GEN_EPS, m1 = v.y + GEN_EPS;
          float e0 = __expf(t * m0), e1 = __expf(t * m1);
          se[2 * q]     += e0;  se[2 * q + 1] += e1;
          sm[2 * q]      = fmaf(m0, e0, sm[2 * q]);
          sm[2 * q + 1]  = fmaf(m1, e1, sm[2 * q + 1]);
        }
      }
    }
  }

  float4 s0 = *(const float4*)(xn + (size_t)node * Fd + f0);
  float4 s1 = *(const float4*)(xn + (size_t)node * Fd + f0 + 4);
  float sf[8] = {s0.x, s0.y, s0.z, s0.w, s1.x, s1.y, s1.z, s1.w};
  unsigned o[8];
  #pragma unroll
  for (int i = 0; i < 8; ++i) o[i] = packhl(sf[i] + sm[i] / (se[i] + 1e-16f));
  *(uint4*)(h2p + (size_t)node * Fd + f0) = *(uint4*)&o[0];
  *(uint4*)(h2p + (size_t)node * Fd + f0 + 4) = *(uint4*)&o[4];
}

// ---- stage 128 K-cols of 64 rows (packed hi|lo u32) into fragment-permuted LDS ----
__device__ __forceinline__ void stage_A128(const unsigned* __restrict__ Ap,
                                           int r0, int rowStride, int kOff,
                                           unsigned short (*Ah)[136],
                                           unsigned short (*Al)[136]) {
  int t = threadIdx.x;
  int row = t >> 2;
  int base = (t & 3) * 32;
  const unsigned* sp = Ap + (size_t)(r0 + row) * rowStride + kOff + base;
  #pragma unroll
  for (int hb = 0; hb < 8; ++hb) {
    int kk0 = hb * 4;
    uint4 a = *(const uint4*)(sp + kk0);
    int d = base + 8 * ((kk0 & 15) >> 2) + 4 * (kk0 >> 4);
    us4 hi = {(unsigned short)a.x, (unsigned short)a.y,
              (unsigned short)a.z, (unsigned short)a.w};
    us4 lo = {(unsigned short)(a.x >> 16), (unsigned short)(a.y >> 16),
              (unsigned short)(a.z >> 16), (unsigned short)(a.w >> 16)};
    *(us4*)&Ah[row][d] = hi;
    *(us4*)&Al[row][d] = lo;
  }
}

// ---------------- fused MLP: gemm1 + LN + relu + gemm2 + residual + {LN/ReLU | xw} ----------------
// mode 0: H += z@W2 + b2; XN/XNh = relu(LN(H))       (layers 0,1)
// mode 2: xwdh = fp16(dis * ((H + z@W2 + b2) @ gw))  (last layer; H not stored)
__global__ __launch_bounds__(256) void mlp_k(const unsigned* __restrict__ Ap,
                                             const unsigned short* __restrict__ W1h,
                                             const unsigned short* __restrict__ W1l,
                                             const float* __restrict__ b1,
                                             const float* __restrict__ g1,
                                             const float* __restrict__ bl1,
                                             const unsigned short* __restrict__ W2h,
                                             const unsigned short* __restrict__ W2l,
                                             const float* __restrict__ b2,
                                             float* __restrict__ H,
                                             const float* __restrict__ gN,
                                             const float* __restrict__ blN,
                                             float* __restrict__ XN,
                                             __half* __restrict__ XNh,
                                             const float* __restrict__ gw,
                                             const float* __restrict__ dis,
                                             __half* __restrict__ xwdh,
                                             int mode) {
  __shared__ unsigned Zu[64][258];          // phase-2 A tile (packed hi|lo), 66KB
  __shared__ float gwS[Fd * Cc];
  unsigned short (*Ah)[136] = (unsigned short(*)[136])&Zu[0][0];
  unsigned short (*Al)[136] = (unsigned short(*)[136])((unsigned short*)&Zu[0][0] + 64 * 136);
  const int t = threadIdx.x;
  const int w = t >> 6, l = t & 63;
  const int g4 = l >> 4, cl = l & 15;
  const int r0 = blockIdx.x * 64;

  if (mode == 2) for (int i = t; i < Fd * Cc; i += 256) gwS[i] = gw[i];

  // ---- phase 1: z = relu(LN(A@W1 + b1)) ----
  stage_A128(Ap, r0, Fd, 0, Ah, Al);
  __syncthreads();
  f32x4 acc[16];
  #pragma unroll
  for (int i = 0; i < 16; ++i) acc[i] = (f32x4){0.f, 0.f, 0.f, 0.f};
  for (int kc = 0; kc < 4; ++kc) {
    bfrag ah = *(const bfrag*)&Ah[16 * w + cl][kc * 32 + g4 * 8];
    bfrag al = *(const bfrag*)&Al[16 * w + cl][kc * 32 + g4 * 8];
    const unsigned short* bh = W1h + ((size_t)(kc * 16) * 64 + l) * 8;
    const unsigned short* bl = W1l + ((size_t)(kc * 16) * 64 + l) * 8;
    #pragma unroll
    for (int tt = 0; tt < 16; ++tt) {
      bfrag vbh = *(const bfrag*)(bh + tt * 512);
      bfrag vbl = *(const bfrag*)(bl + tt * 512);
      acc[tt] = __builtin_amdgcn_mfma_f32_16x16x32_bf16(ah, vbh, acc[tt], 0, 0, 0);
      acc[tt] = __builtin_amdgcn_mfma_f32_16x16x32_bf16(ah, vbl, acc[tt], 0, 0, 0);
      acc[tt] = __builtin_amdgcn_mfma_f32_16x16x32_bf16(al, vbh, acc[tt], 0, 0, 0);
    }
  }
  __syncthreads();                          // all waves done reading A LDS

  {
    float bcol[16], gcol[16], blc[16];
    #pragma unroll
    for (int tt = 0; tt < 16; ++tt) {
      int c = 16 * tt + cl;
      bcol[tt] = b1[c]; gcol[tt] = g1[c]; blc[tt] = bl1[c];
    }
    #pragma unroll
    for (int j = 0; j < 4; ++j) {
      float x[16];
      float s = 0.f, q = 0.f;
      #pragma unroll
      for (int tt = 0; tt < 16; ++tt) {
        x[tt] = acc[tt][j] + bcol[tt];
        s += x[tt];
        q = fmaf(x[tt], x[tt], q);
      }
      #pragma unroll
      for (int m = 8; m >= 1; m >>= 1) { s += __shfl_xor(s, m); q += __shfl_xor(q, m); }
      float mu = s * (1.f / 256.f);
      float rs = rsqrtf(q * (1.f / 256.f) - mu * mu + LN_EPS);
      int rl = 16 * w + 4 * g4 + j;
      #pragma unroll
      for (int tt = 0; tt < 16; ++tt) {
        float z = fmaxf((x[tt] - mu) * rs * gcol[tt] + blc[tt], 0.f);
        Zu[rl][16 * tt + cl] = packhl(z);
      }
    }
  }
  __syncthreads();                          // z tile complete

  // ---- phase 2: out = z @ W2 ----
  f32x4 acc2[8];
  #pragma unroll
  for (int i = 0; i < 8; ++i) acc2[i] = (f32x4){0.f, 0.f, 0.f, 0.f};
  for (int kf = 0; kf < 8; ++kf) {
    uint4 p0 = *(const uint4*)&Zu[16 * w + cl][kf * 32 + 4 * g4];
    uint4 p1 = *(const uint4*)&Zu[16 * w + cl][kf * 32 + 4 * g4 + 16];
    unsigned pv[8] = {p0.x, p0.y, p0.z, p0.w, p1.x, p1.y, p1.z, p1.w};
    bfrag ah2, al2;
    #pragma unroll
    for (int i = 0; i < 8; ++i) {
      ah2[i] = (short)(pv[i] & 0xFFFF);
      al2[i] = (short)(pv[i] >> 16);
    }
    const unsigned short* bh = W2h + ((size_t)(kf * 8) * 64 + l) * 8;
    const unsigned short* bl = W2l + ((size_t)(kf * 8) * 64 + l) * 8;
    #pragma unroll
    for (int tt = 0; tt < 8; ++tt) {
      bfrag vbh = *(const bfrag*)(bh + tt * 512);
      bfrag vbl = *(const bfrag*)(bl + tt * 512);
      acc2[tt] = __builtin_amdgcn_mfma_f32_16x16x32_bf16(ah2, vbh, acc2[tt], 0, 0, 0);
      acc2[tt] = __builtin_amdgcn_mfma_f32_16x16x32_bf16(ah2, vbl, acc2[tt], 0, 0, 0);
      acc2[tt] = __builtin_amdgcn_mfma_f32_16x16x32_bf16(al2, vbh, acc2[tt], 0, 0, 0);
    }
  }

  // ---- epilogue2 ----
  float bcol[8], gcol[8], blc[8];
  #pragma unroll
  for (int tt = 0; tt < 8; ++tt) {
    int c = 16 * tt + cl;
    bcol[tt] = b2[c];
    if (mode == 0) { gcol[tt] = gN[c]; blc[tt] = blN[c]; }
  }
  #pragma unroll
  for (int j = 0; j < 4; ++j) {
    int row = r0 + 16 * w + 4 * g4 + j;
    float x[8];
    float s = 0.f, q = 0.f;
    #pragma unroll
    for (int tt = 0; tt < 8; ++tt) {
      size_t off = (size_t)row * Fd + 16 * tt + cl;
      float hv = H[off] + acc2[tt][j] + bcol[tt];
      x[tt] = hv;
      if (mode == 0) {
        H[off] = hv;
        s += hv;
        q = fmaf(hv, hv, q);
      }
    }
    if (mode == 0) {
      #pragma unroll
      for (int m = 8; m >= 1; m >>= 1) { s += __shfl_xor(s, m); q += __shfl_xor(q, m); }
      float mu = s * (1.f / 128.f);
      float rs = rsqrtf(q * (1.f / 128.f) - mu * mu + LN_EPS);
      #pragma unroll
      for (int tt = 0; tt < 8; ++tt) {
        float z = fmaxf((x[tt] - mu) * rs * gcol[tt] + blc[tt], 0.f);
        size_t off = (size_t)row * Fd + 16 * tt + cl;
        XN[off] = z;
        XNh[off] = __float2half_rn(z);
      }
    } else {
      float p[Cc];
      #pragma unroll
      for (int c = 0; c < Cc; ++c) p[c] = 0.f;
      #pragma unroll
      for (int tt = 0; tt < 8; ++tt) {
        const float* wr = &gwS[(16 * tt + cl) * Cc];
        float xv = x[tt];
        #pragma unroll
        for (int c = 0; c < Cc; ++c) p[c] = fmaf(xv, wr[c], p[c]);
      }
      #pragma unroll
      for (int m = 8; m >= 1; m >>= 1)
        #pragma unroll
        for (int c = 0; c < Cc; ++c) p[c] += __shfl_xor(p[c], m);
      float v = p[0];
      #pragma unroll
      for (int c = 1; c < Cc; ++c) if (cl == c) v = p[c];
      float v2 = p[16];
      #pragma unroll
      for (int c = 17; c < Cc; ++c) if (cl == c - 16) v2 = p[c];
      float dvr = dis[row];
      xwdh[(size_t)row * 32 + cl] = __float2half_rn(v * dvr);
      if (cl < 4) xwdh[(size_t)row * 32 + 16 + cl] = __float2half_rn(v2 * dvr);
    }
  }
}

// ---------------- GCN output ----------------
__global__ __launch_bounds__(256) void gcn_out_k(const __half* __restrict__ xwdh,
                                                 const int* __restrict__ row_ptr,
                                                 const uint2* __restrict__ cole,
                                                 const float* __restrict__ dis,
                                                 const float* __restrict__ bias,
                                                 float* __restrict__ out) {
  int node = blockIdx.x * 4 + (threadIdx.x >> 6);
  int lane = threadIdx.x & 63;
  int grp = lane / Cc, c = lane % Cc;       // grp 0..2 active, 3 = idle tail lanes
  float dv = dis[node];
  float acc = 0.f;
  int beg = row_ptr[node], end = row_ptr[node + 1];
  if (grp < 3) {
    for (int j = beg + grp; j < end; j += 3) {
      uint2 ce = cole[j];
      acc += __uint_as_float(ce.y) * __half2float(xwdh[(size_t)ce.x * 32 + c]);
    }
  }
  int l20 = lane + 20 < 64 ? lane + 20 : lane;
  int l40 = lane + 40 < 64 ? lane + 40 : lane;
  float tot = acc + __shfl(acc, l20) + __shfl(acc, l40);
  float val = 0.f;
  if (lane < Cc)
    val = dv * tot + dv * __half2float(xwdh[(size_t)node * 32 + c]) + bias[c];
  float red = (lane < Cc) ? val : -INFINITY;
  #pragma unroll
  for (int m = 32; m >= 1; m >>= 1) red = fmaxf(red, __shfl_xor(red, m));
  float ex = (lane < Cc) ? __expf(val - red) : 0.f;
  #pragma unroll
  for (int m = 32; m >= 1; m >>= 1) ex += __shfl_xor(ex, m);
  float ls = __logf(ex);
  if (lane < Cc) out[(size_t)node * Cc + c] = val - red - ls;
}

// ---------------- host ----------------
extern "C" void kernel_launch(void* const* d_in, const int* in_sizes, int n_in,
                              void* d_out, int out_size, void* d_ws, size_t ws_size,
                              hipStream_t stream) {
  const int*   x_ids = (const int*)d_in[0];
  const int*   ei    = (const int*)d_in[1];
  const int*   srcp  = ei;
  const int*   dstp  = ei + Ee;
  const float* eattr = (const float*)d_in[2];
  const float* emb   = (const float*)d_in[3];
  const float* ln_g  = (const float*)d_in[4];
  const float* ln_b  = (const float*)d_in[5];
  const float* tpar  = (const float*)d_in[6];
  const float* w1    = (const float*)d_in[7];
  const float* b1    = (const float*)d_in[8];
  const float* mg    = (const float*)d_in[9];
  const float* mb    = (const float*)d_in[10];
  const float* w2    = (const float*)d_in[11];
  const float* b2    = (const float*)d_in[12];
  const float* gw    = (const float*)d_in[13];
  const float* gb    = (const float*)d_in[14];
  float* out = (float*)d_out;

  char* ws = (char*)d_ws;
  float* h    = (float*)ws;  ws += (size_t)Nn * Fd * 4;
  float* xn   = (float*)ws;  ws += (size_t)Nn * Fd * 4;
  __half* xnh = (__half*)ws; ws += (size_t)Nn * Fd * 2;
  __half* xwdh = (__half*)ws; ws += (size_t)Nn * 32 * 2;
  float* dis  = (float*)ws;  ws += (size_t)Nn * 4;
  unsigned* h2p = (unsigned*)ws; ws += (size_t)Nn * Fd * 4;
  unsigned short* w1h = (unsigned short*)ws; ws += (size_t)3 * Fd * Hid * 2;
  unsigned short* w1l = (unsigned short*)ws; ws += (size_t)3 * Fd * Hid * 2;
  unsigned short* w2h = (unsigned short*)ws; ws += (size_t)3 * Fd * Hid * 2;
  unsigned short* w2l = (unsigned short*)ws; ws += (size_t)3 * Fd * Hid * 2;
  int* row_ptr = (int*)ws; ws += (size_t)(Nn + 16) * 4;
  int* cnt   = (int*)ws;   ws += (size_t)2 * Nn * 4;    // counts + cursors
  uint2* cole = (uint2*)ws; ws += (size_t)Ee * 8;
  int* bsum  = (int*)ws;   ws += 256 * 4;
  if ((size_t)(ws - (char*)d_ws) > ws_size) return;  // workspace too small

  constexpr int NB = (Nn + 255) / 256;  // 157

  prep_w_k<<<(3 * Fd * Hid + 255) / 256, 256, 0, stream>>>(w1, w2, w1h, w1l, w2h, w2l);

  // CSR by destination (rebuilt every call; deterministic work)
  zero_int_k<<<2 * NB, 256, 0, stream>>>(cnt, 2 * Nn);
  count_k<<<2500, 256, 0, stream>>>(dstp, cnt);
  blocksum_k<<<NB, 256, 0, stream>>>(cnt, bsum, Nn);
  scanbsum_k<<<1, 256, 0, stream>>>(bsum, NB);
  scanfinal_k<<<NB, 256, 0, stream>>>(cnt, bsum, row_ptr, Nn);
  scatter_k<<<2500, 256, 0, stream>>>(srcp, dstp, eattr, row_ptr, cnt + Nn, cole);
  deg_dis_k<<<NB, 256, 0, stream>>>(row_ptr, cole, dis);

  embed_ln_k<<<Nn / 4, 256, 0, stream>>>(x_ids, emb, ln_g, ln_b, h, xn, xnh);

  for (int i = 0; i < 3; ++i) {
    gen_agg_k<<<Nn / 16, 256, 0, stream>>>(xn, xnh, row_ptr, cole, tpar + i, h2p);
    mlp_k<<<Nn / 64, 256, 0, stream>>>(h2p,
        w1h + (size_t)i * Fd * Hid, w1l + (size_t)i * Fd * Hid,
        b1 + i * Hid, mg + i * Hid, mb + i * Hid,
        w2h + (size_t)i * Fd * Hid, w2l + (size_t)i * Fd * Hid,
        b2 + i * Fd, h,
        ln_g + (i + 1) * Fd, ln_b + (i + 1) * Fd,
        xn, xnh, gw, dis, xwdh, (i < 2) ? 0 : 2);
  }

  gcn_out_k<<<Nn / 4, 256, 0, stream>>>(xwdh, row_ptr, cole, dis, gb, out);
}